// Round 10
// baseline (225.053 us; speedup 1.0000x reference)
//
#include <hip/hip_runtime.h>
#include <math.h>

typedef unsigned int u32;
typedef unsigned long long u64;

#define BB 16
#define NANCH 17064
#define NGRP 4266          // NANCH / 4
#define NTOP 1000
#define NWORD 16
#define NOUT 100
#define NBIN13 8192        // 13-bit coarse bins (fits LDS)
#define NSPLIT_R 8         // rank blocks per batch (8*256 = 2048 >= typical C)
#define CANDCAP 4096       // LDS candidate cap (32 KB, aliases refined hist)

__device__ __forceinline__ u32 fmap(float v) {
    u32 u = __float_as_uint(v);
    return (u & 0x80000000u) ? ~u : (u | 0x80000000u);
}
__device__ __forceinline__ float funmap(u32 u) {
    u32 b = (u & 0x80000000u) ? (u & 0x7FFFFFFFu) : ~u;
    return __uint_as_float(b);
}

// ---------------------------------------------------------------- kernel A
// Round-5..9 proven: prefetch 20 float4 -> regs + sched_barrier, two-stage
// shfl_xor argmax, fused per-block LDS coarse histogram (<=256 keys/block,
// no hot-bin serialization) + global merge of nonzero bins.
__global__ void __launch_bounds__(256) k_anchor(
        const float* __restrict__ c0, const float* __restrict__ c1,
        const float* __restrict__ c2, const float* __restrict__ c3,
        const float* __restrict__ c4,
        const float* __restrict__ r0, const float* __restrict__ r1,
        const float* __restrict__ r2, const float* __restrict__ r3,
        const float* __restrict__ r4,
        u32* __restrict__ akey, int* __restrict__ aclass,
        float* __restrict__ abox, u32* __restrict__ ghist) {
    __shared__ u32 h1[NBIN13];               // 32 KB
    int tid = threadIdx.x;
    int b = blockIdx.y;
    int gt = blockIdx.x * 256 + tid;         // 4 * NGRP = 17064 used
    bool valid = gt < 4 * NGRP;

    for (int i = tid; i < NBIN13; i += 256) h1[i] = 0;
    __syncthreads();

    if (valid) {
        int p = gt >> 2, cs = gt & 3;        // group, class-quarter
        int a = p * 4;

        const float *cp, *rp;
        int loc, wl, h, stride, half;
        if (a < 12800)      { loc = a;         wl = 7; h = 100; stride = 8;   half = 4;  cp = c0; rp = r0; }
        else if (a < 16000) { loc = a - 12800; wl = 6; h = 50;  stride = 16;  half = 8;  cp = c1; rp = r1; }
        else if (a < 16800) { loc = a - 16000; wl = 5; h = 25;  stride = 32;  half = 16; cp = c2; rp = r2; }
        else if (a < 17008) { loc = a - 16800; wl = 4; h = 13;  stride = 64;  half = 32; cp = c3; rp = r3; }
        else                { loc = a - 17008; wl = 3; h = 7;   stride = 128; half = 64; cp = c4; rp = r4; }
        int y = loc >> wl, x = loc & ((1 << wl) - 1);
        int hw = h << wl, hwq = hw >> 2;

        const float4* cb4 = (const float4*)(cp + (size_t)b * 80 * hw +
                                            (size_t)cs * 20 * hw + loc);
        // ---- issue ALL loads up front (static indices -> registers) ----
        float4 buf[20];
#pragma unroll
        for (int c = 0; c < 20; ++c) buf[c] = cb4[(size_t)c * hwq];
        const float4* rb4 = (const float4*)(rp + (size_t)b * 4 * hw + loc);
        float4 gl, gt_, gr, gb;
        if (cs == 0) {
            gl = rb4[0]; gt_ = rb4[hwq]; gr = rb4[2 * hwq]; gb = rb4[3 * hwq];
        }
        __builtin_amdgcn_sched_barrier(0);   // keep loads above the compute

        int cbase = cs * 20;
        float m0 = buf[0].x, m1 = buf[0].y, m2 = buf[0].z, m3 = buf[0].w;
        int a0 = cbase, a1 = cbase, a2 = cbase, a3 = cbase;
#pragma unroll
        for (int c = 1; c < 20; ++c) {
            float4 u = buf[c];
            int cc = cbase + c;
            if (u.x > m0) { m0 = u.x; a0 = cc; }
            if (u.y > m1) { m1 = u.y; a1 = cc; }
            if (u.z > m2) { m2 = u.z; a2 = cc; }
            if (u.w > m3) { m3 = u.w; a3 = cc; }
        }
        // stage 1: xor-1 partner; lower class-quarter wins ties
        {
            bool low = (cs & 1) == 0;
            float pm; int pa; bool tk;
            pm = __shfl_xor(m0, 1); pa = __shfl_xor(a0, 1);
            tk = low ? (m0 >= pm) : (m0 > pm); m0 = tk ? m0 : pm; a0 = tk ? a0 : pa;
            pm = __shfl_xor(m1, 1); pa = __shfl_xor(a1, 1);
            tk = low ? (m1 >= pm) : (m1 > pm); m1 = tk ? m1 : pm; a1 = tk ? a1 : pa;
            pm = __shfl_xor(m2, 1); pa = __shfl_xor(a2, 1);
            tk = low ? (m2 >= pm) : (m2 > pm); m2 = tk ? m2 : pm; a2 = tk ? a2 : pa;
            pm = __shfl_xor(m3, 1); pa = __shfl_xor(a3, 1);
            tk = low ? (m3 >= pm) : (m3 > pm); m3 = tk ? m3 : pm; a3 = tk ? a3 : pa;
        }
        // stage 2: xor-2 partner; lower half wins ties
        {
            bool low = (cs & 2) == 0;
            float pm; int pa; bool tk;
            pm = __shfl_xor(m0, 2); pa = __shfl_xor(a0, 2);
            tk = low ? (m0 >= pm) : (m0 > pm); m0 = tk ? m0 : pm; a0 = tk ? a0 : pa;
            pm = __shfl_xor(m1, 2); pa = __shfl_xor(a1, 2);
            tk = low ? (m1 >= pm) : (m1 > pm); m1 = tk ? m1 : pm; a1 = tk ? a1 : pa;
            pm = __shfl_xor(m2, 2); pa = __shfl_xor(a2, 2);
            tk = low ? (m2 >= pm) : (m2 > pm); m2 = tk ? m2 : pm; a2 = tk ? a2 : pa;
            pm = __shfl_xor(m3, 2); pa = __shfl_xor(a3, 2);
            tk = low ? (m3 >= pm) : (m3 > pm); m3 = tk ? m3 : pm; a3 = tk ? a3 : pa;
        }
        if (cs == 0) {
            int idx = b * NANCH + a;
            u32 km0 = fmap(m0), km1 = fmap(m1), km2 = fmap(m2), km3 = fmap(m3);
            *(uint4*)(akey + idx) = make_uint4(km0, km1, km2, km3);
            *(int4*)(aclass + idx) = make_int4(a0 + 1, a1 + 1, a2 + 1, a3 + 1);
            atomicAdd(&h1[km0 >> 19], 1u);
            atomicAdd(&h1[km1 >> 19], 1u);
            atomicAdd(&h1[km2 >> 19], 1u);
            atomicAdd(&h1[km3 >> 19], 1u);
            float cy = (float)(y * stride + half);
            float cx0 = (float)(x * stride + half);
            float gls[4] = {gl.x, gl.y, gl.z, gl.w};
            float gts[4] = {gt_.x, gt_.y, gt_.z, gt_.w};
            float grs[4] = {gr.x, gr.y, gr.z, gr.w};
            float gbs[4] = {gb.x, gb.y, gb.z, gb.w};
#pragma unroll
            for (int k = 0; k < 4; ++k) {
                float cx = cx0 + (float)(k * stride);
                *(float4*)(abox + (size_t)(idx + k) * 4) =
                    make_float4(cx - gls[k], cy - gts[k], cx + grs[k], cy + gbs[k]);
            }
        }
    }
    __syncthreads();
    // merge nonzero bins to global (few tens per block -> low contention)
    u32* gh = ghist + (size_t)b * NBIN13;
    for (int i = tid; i < NBIN13; i += 256) {
        u32 c = h1[i];
        if (c) atomicAdd(&gh[i], c);
    }
}

// ---------------------------------------------------------------- kernel D
// FUSED select+rank, now with INLINE REFINED 26-bit threshold (rounds 2-7
// proven math) to shrink C ~3400 -> ~1100 and cut the rank loop 3x.
// 8x16 blocks. Per block:
//   1) T13 + A from L2-hot ghist (segment sums, suffix scan)
//   2) refined LDS hist of bin-T13 keys (bits 18:6, spread -> no hot bins)
//      -> t2 with A + suffix2 >= NTOP -> thr26 = (T13<<13)|t2
//   3) deterministic LDS candidate build (count -> prefix scan -> place);
//      cand[4096] ALIASES the refined-hist LDS (disjoint lifetimes)
//   4) exact rank via 8-way-unrolled LDS broadcast reads; write outputs.
__global__ void __launch_bounds__(256) k_rank(
        const u32* __restrict__ akey, const u32* __restrict__ ghist,
        const int* __restrict__ aclass, const float* __restrict__ abox,
        float* __restrict__ tscore, int* __restrict__ tclass,
        float* __restrict__ tbox, u32* __restrict__ maxcU) {
    __shared__ u32 h2[NBIN13];          // 32 KB; reused as u64 cand[4096]
    __shared__ u32 seg[256];
    __shared__ u32 binb[32];
    __shared__ int Gs;
    __shared__ u32 T13s, As, thrS;
    u64* cand = (u64*)h2;
    int b = blockIdx.y, s = blockIdx.x, t = threadIdx.x;
    const u32* gh = ghist + (size_t)b * NBIN13;
    const uint4* ak4 = (const uint4*)(akey + (size_t)b * NANCH);

    // ---- phase 1: T13 + A (segment sums from global, suffix scan) ----
    u32 sum = 0;
    {
        const uint4* g4 = (const uint4*)(gh + t * 32);
#pragma unroll
        for (int j = 0; j < 8; ++j) {
            uint4 q = g4[j];
            sum += q.x + q.y + q.z + q.w;
        }
    }
    seg[t] = sum;
    if (t == 0) Gs = 0;
    __syncthreads();
    for (int off = 1; off < 256; off <<= 1) {        // inclusive suffix scan
        u32 v = seg[t];
        u32 add = (t + off < 256) ? seg[t + off] : 0u;
        __syncthreads();
        seg[t] = v + add;
        __syncthreads();
    }
    if (seg[t] >= NTOP) atomicMax(&Gs, t);
    __syncthreads();
    int G = Gs;
    u32 hi = (G < 255) ? seg[G + 1] : 0u;            // suffix above segment G
    if (t < 32) binb[t] = gh[G * 32 + t];
    __syncthreads();
    if (t == 0) {
        u32 acc = hi, A = hi;
        int T13 = G * 32;
        for (int i = 31; i >= 0; --i) {
            A = acc;                                  // suffix strictly above bin i
            acc += binb[i];
            if (acc >= NTOP) { T13 = G * 32 + i; break; }
        }
        T13s = (u32)T13; As = A;
        Gs = 0;                                       // re-init for phase 2
    }
    __syncthreads();
    u32 T13 = T13s, A = As;

    // ---- phase 2: refined hist of bin-T13 keys (bits 18:6) -> thr26 ----
    for (int i = t; i < NBIN13; i += 256) h2[i] = 0;
    __syncthreads();
    for (int i = t; i < NGRP; i += 256) {
        uint4 k4 = ak4[i];
        if ((k4.x >> 19) == T13) atomicAdd(&h2[(k4.x >> 6) & (NBIN13 - 1)], 1u);
        if ((k4.y >> 19) == T13) atomicAdd(&h2[(k4.y >> 6) & (NBIN13 - 1)], 1u);
        if ((k4.z >> 19) == T13) atomicAdd(&h2[(k4.z >> 6) & (NBIN13 - 1)], 1u);
        if ((k4.w >> 19) == T13) atomicAdd(&h2[(k4.w >> 6) & (NBIN13 - 1)], 1u);
    }
    __syncthreads();
    u32 target = NTOP - A;                            // >= 1 by construction
    u32 s2 = 0;
#pragma unroll
    for (int j = 0; j < 32; ++j) s2 += h2[t * 32 + ((j + t) & 31)];  // bank-free
    seg[t] = s2;
    __syncthreads();
    for (int off = 1; off < 256; off <<= 1) {        // inclusive suffix scan
        u32 v = seg[t];
        u32 add = (t + off < 256) ? seg[t + off] : 0u;
        __syncthreads();
        seg[t] = v + add;
        __syncthreads();
    }
    if (seg[t] >= target) atomicMax(&Gs, t);
    __syncthreads();
    int G2 = Gs;
    u32 hi2 = (G2 < 255) ? seg[G2 + 1] : 0u;
    if (t == 0) {
        u32 acc = hi2;
        int t2 = G2 * 32;
        for (int i = 31; i >= 0; --i) {
            acc += h2[G2 * 32 + i];
            if (acc >= target) { t2 = G2 * 32 + i; break; }
        }
        thrS = (T13 << 13) | (u32)t2;
    }
    __syncthreads();
    u32 thr = thrS;

    // ---- phase 3: deterministic candidate build (cand aliases h2) ----
    u32 cnt = 0;
    for (int i = t; i < NGRP; i += 256) {
        uint4 k4 = ak4[i];
        cnt += (k4.x >> 6) >= thr;
        cnt += (k4.y >> 6) >= thr;
        cnt += (k4.z >> 6) >= thr;
        cnt += (k4.w >> 6) >= thr;
    }
    __syncthreads();                    // h2 reads done -> safe to overwrite
    seg[t] = cnt;
    __syncthreads();
    for (int off = 1; off < 256; off <<= 1) {        // inclusive PREFIX scan
        u32 v = seg[t];
        u32 add = (t >= off) ? seg[t - off] : 0u;
        __syncthreads();
        seg[t] = v + add;
        __syncthreads();
    }
    u32 pos = seg[t] - cnt;             // exclusive offset, thread-major order
    int C = (int)seg[255];
    if (C > CANDCAP) C = CANDCAP;
    for (int i = t; i < NGRP; i += 256) {
        uint4 k4 = ak4[i];
        u32 kk[4] = {k4.x, k4.y, k4.z, k4.w};
#pragma unroll
        for (int jj = 0; jj < 4; ++jj) {
            if ((kk[jj] >> 6) >= thr) {
                if (pos < CANDCAP)
                    cand[pos] = ((u64)kk[jj] << 32) |
                                (u64)(0xFFFFFFFFu - (u32)(4 * i + jj));
                ++pos;
            }
        }
    }
    __syncthreads();

    // ---- phase 4: exact rank from LDS (broadcast reads); write outputs ----
    for (int base = s * 256; base < C; base += NSPLIT_R * 256) {
        int i = base + t;
        bool have = i < C;
        u64 my = have ? cand[i] : 0ull;
        int q0 = 0, q1 = 0, q2 = 0, q3 = 0, q4 = 0, q5 = 0, q6 = 0, q7 = 0;
        int j = 0;
        for (; j + 8 <= C; j += 8) {
            u64 v0 = cand[j + 0], v1 = cand[j + 1];
            u64 v2 = cand[j + 2], v3 = cand[j + 3];
            u64 v4 = cand[j + 4], v5 = cand[j + 5];
            u64 v6 = cand[j + 6], v7 = cand[j + 7];
            q0 += v0 > my; q1 += v1 > my; q2 += v2 > my; q3 += v3 > my;
            q4 += v4 > my; q5 += v5 > my; q6 += v6 > my; q7 += v7 > my;
        }
        for (; j < C; ++j) q0 += cand[j] > my;
        int rank = ((q0 + q1) + (q2 + q3)) + ((q4 + q5) + (q6 + q7));
        u32 mymax = 0;  // identity under monotone map
        if (have && rank < NTOP) {
            u32 a = 0xFFFFFFFFu - (u32)(my & 0xFFFFFFFFull);
            int src = b * NANCH + (int)a;
            int dst = b * NTOP + rank;
            float logit = funmap((u32)(my >> 32));
            float sc = 1.0f / (1.0f + expf(-logit));
            float b0 = abox[src * 4 + 0], b1 = abox[src * 4 + 1];
            float b2 = abox[src * 4 + 2], b3 = abox[src * 4 + 3];
            tscore[dst] = sc;
            tclass[dst] = aclass[src];
            tbox[dst * 4 + 0] = b0;
            tbox[dst * 4 + 1] = b1;
            tbox[dst * 4 + 2] = b2;
            tbox[dst * 4 + 3] = b3;
            if (sc >= 0.05f)
                mymax = fmap(fmaxf(fmaxf(b0, b1), fmaxf(b2, b3)));
        }
        for (int off = 32; off > 0; off >>= 1) {
            u32 o = (u32)__shfl_down((int)mymax, off);
            mymax = mymax > o ? mymax : o;
        }
        if ((t & 63) == 0) atomicMax(&maxcU[b], mymax);
    }
}

// ---------------------------------------------------------------- kernel F
// upper-triangle tiles only (136 of 256). Divide-free DIoU test:
// diou > 0.6  <=>  inter*odg - idg*U > 0.6*U*odg   (U>0, odg>0)  [proven r2]
__global__ void k_sup(const float* __restrict__ tbox, const int* __restrict__ tclass,
                      const u32* __restrict__ maxcU, u64* __restrict__ sup) {
    int u = blockIdx.x, b = blockIdx.y;
    int ti = 0, rem = u;
    while (rem >= NWORD - ti) { rem -= NWORD - ti; ++ti; }
    int tj = ti + rem;
    int t = threadIdx.x;
    __shared__ double jx1[64], jy1[64], jx2[64], jy2[64], jcx[64], jcy[64], jar[64];
    double mc1 = (double)funmap(maxcU[b]) + 1.0;
    int j = tj * 64 + t;
    if (j < NTOP) {
        const float* bx = tbox + (size_t)(b * NTOP + j) * 4;
        double o = (double)tclass[b * NTOP + j] * mc1;
        double x1 = (double)bx[0] + o, y1 = (double)bx[1] + o;
        double x2 = (double)bx[2] + o, y2 = (double)bx[3] + o;
        jx1[t] = x1; jy1[t] = y1; jx2[t] = x2; jy2[t] = y2;
        jcx[t] = (x1 + x2) * 0.5; jcy[t] = (y1 + y2) * 0.5;
        jar[t] = (x2 - x1 + 1.0) * (y2 - y1 + 1.0);
    }
    __syncthreads();
    int i = ti * 64 + t;
    if (i >= NTOP) return;
    const float* bx = tbox + (size_t)(b * NTOP + i) * 4;
    double o = (double)tclass[b * NTOP + i] * mc1;
    double ix1 = (double)bx[0] + o, iy1 = (double)bx[1] + o;
    double ix2 = (double)bx[2] + o, iy2 = (double)bx[3] + o;
    double icx = (ix1 + ix2) * 0.5, icy = (iy1 + iy2) * 0.5;
    double iar = (ix2 - ix1 + 1.0) * (iy2 - iy1 + 1.0);
    u64 bits = 0;
    int jbase = tj * 64;
    for (int jj = 0; jj < 64; ++jj) {
        int jg = jbase + jj;
        if (jg >= NTOP) break;
        if (jg <= i) continue;
        double xm = fmax(ix1, jx1[jj]), ym = fmax(iy1, jy1[jj]);
        double xM = fmin(ix2, jx2[jj]), yM = fmin(iy2, jy2[jj]);
        double inter = fmax(xM - xm, 0.0) * fmax(yM - ym, 0.0);
        double U = iar + jar[jj] - inter;
        double dx = icx - jcx[jj], dy = icy - jcy[jj];
        double idg = dx * dx + dy * dy;
        double ox = fmax(ix2, jx2[jj]) - fmin(ix1, jx1[jj]);
        double oy = fmax(iy2, jy2[jj]) - fmin(iy1, jy1[jj]);
        double odg = fmax(ox * ox + oy * oy, 1e-12);
        if (inter * odg - idg * U > 0.6 * (U * odg)) bits |= (1ull << jj);
    }
    sup[(size_t)(b * NTOP + i) * NWORD + tj] = bits;
}

// ---------------------------------------------------------------- kernel G
// Wave-synchronous greedy scan; 256 threads — waves 1-3 double-buffer
// prefetch tile t+1 while wave 0 scans tile t. [round-5 proven]
__global__ void __launch_bounds__(256) k_scan(
        const u64* __restrict__ sup, const float* __restrict__ tscore,
        const int* __restrict__ tclass, const float* __restrict__ tbox,
        float* __restrict__ out) {
    int b = blockIdx.x, tid = threadIdx.x;
    int lane = tid & 63;
    __shared__ u64 tl[2][64 * 17];           // double-buffered padded tiles
    __shared__ float sc_s[1024];
    __shared__ int kept_lds[NOUT];
    __shared__ int kept_sh;
    const u64* supb = sup + (size_t)b * NTOP * NWORD;
    for (int i = tid; i < 1024; i += 256)
        sc_s[i] = (i < NTOP) ? tscore[b * NTOP + i] : -1.0f;
    if (tid == 0) kept_sh = 0;
    // prologue: all threads load tile 0
    for (int q = 0; q < 4; ++q) {
        int e = q * 256 + tid;
        int rr = e >> 4, w = e & 15;
        tl[0][rr * 17 + w] = (rr < NTOP) ? supb[(size_t)rr * 16 + w] : 0ull;
    }
    __syncthreads();
    u64 remw = 0;                            // wave0: lane w<16 = removed word w
    int kept = 0;
    for (int t = 0; t < NWORD; ++t) {
        int cur = t & 1;
        if (tid >= 64) {                     // waves 1-3: prefetch tile t+1
            if (t + 1 < NWORD) {
                int r1 = (t + 1) * 64;
                for (int e = tid - 64; e < 1024; e += 192) {
                    int rr = r1 + (e >> 4), w = e & 15;
                    tl[cur ^ 1][(e >> 4) * 17 + w] =
                        (rr < NTOP) ? supb[(size_t)rr * 16 + w] : 0ull;
                }
            }
        } else {                             // wave 0: greedy scan of tile t
            int r0 = t * 64;
            int r = r0 + lane;               // r <= 1023, sc_s padded
            float s = sc_s[r];
            u64 vmask = __ballot(s >= 0.05f);
            u64 M = tl[cur][lane * 17 + t];
            u64 rem_t = __shfl(remw, t);
            u64 cnd = vmask & ~rem_t;
            u64 keepmask = 0;
            while (cnd) {
                int k = __ffsll(cnd) - 1;
                keepmask |= 1ull << k;
                if (lane == 0) kept_lds[kept] = r0 + k;
                ++kept;
                if (kept >= NOUT) break;
                u64 Mk = __shfl(M, k);
                cnd &= ~(Mk | (1ull << k));
            }
            if (lane < NWORD) {
                u64 km = keepmask;
                while (km) {
                    int k = __ffsll(km) - 1;
                    km &= km - 1;
                    remw |= tl[cur][k * 17 + lane];
                }
            }
            if (lane == 0) kept_sh = kept;
        }
        __syncthreads();
        if (kept_sh >= NOUT) break;          // block-uniform
    }
    float* os = out + b * NOUT;
    float* oc = out + BB * NOUT + b * NOUT;
    float* ob = out + 2 * BB * NOUT + (size_t)b * NOUT * 4;
    for (int i = tid; i < NOUT; i += 256) { os[i] = -2.0f; oc[i] = -2.0f; }
    for (int i = tid; i < NOUT * 4; i += 256) ob[i] = -2.0f;
    __syncthreads();
    int ncopy = kept_sh < NOUT ? kept_sh : NOUT;
    for (int r = tid; r < ncopy; r += 256) {
        int i = kept_lds[r];
        os[r] = tscore[b * NTOP + i];
        oc[r] = (float)tclass[b * NTOP + i];
        ob[r * 4 + 0] = tbox[(size_t)(b * NTOP + i) * 4 + 0];
        ob[r * 4 + 1] = tbox[(size_t)(b * NTOP + i) * 4 + 1];
        ob[r * 4 + 2] = tbox[(size_t)(b * NTOP + i) * 4 + 2];
        ob[r * 4 + 3] = tbox[(size_t)(b * NTOP + i) * 4 + 3];
    }
}

// ---------------------------------------------------------------- launch
extern "C" void kernel_launch(void* const* d_in, const int* in_sizes, int n_in,
                              void* d_out, int out_size, void* d_ws, size_t ws_size,
                              hipStream_t stream) {
    (void)in_sizes; (void)n_in; (void)out_size; (void)ws_size;
    const float* cls[5];
    const float* reg[5];
    for (int i = 0; i < 5; ++i) {
        cls[i] = (const float*)d_in[2 * i];
        reg[i] = (const float*)d_in[2 * i + 1];
    }
    float* out = (float*)d_out;

    char* ws = (char*)d_ws;
    // ---- zero-init region (single memset): ghist + maxcU ----
    u32* ghist = (u32*)ws;           ws += (size_t)BB * NBIN13 * sizeof(u32); // 512 KB
    u32* maxcU = (u32*)ws;           ws += 64;
    size_t zbytes = (size_t)BB * NBIN13 * sizeof(u32) + 64;
    // ---- rest (written before read) ----
    u64* sup = (u64*)ws;             ws += (size_t)BB * NTOP * NWORD * sizeof(u64);
    u32* akey = (u32*)ws;            ws += (size_t)BB * NANCH * sizeof(u32);
    int* aclass = (int*)ws;          ws += (size_t)BB * NANCH * sizeof(int);
    float* abox = (float*)ws;        ws += (size_t)BB * NANCH * 4 * sizeof(float);
    float* tscore = (float*)ws;      ws += (size_t)BB * NTOP * sizeof(float);
    int* tclass = (int*)ws;          ws += (size_t)BB * NTOP * sizeof(int);
    float* tbox = (float*)ws;        ws += (size_t)BB * NTOP * 4 * sizeof(float);

    hipMemsetAsync(ghist, 0, zbytes, stream);

    k_anchor<<<dim3((4 * NGRP + 255) / 256, BB), 256, 0, stream>>>(
        cls[0], cls[1], cls[2], cls[3], cls[4],
        reg[0], reg[1], reg[2], reg[3], reg[4],
        akey, aclass, abox, ghist);
    k_rank<<<dim3(NSPLIT_R, BB), 256, 0, stream>>>(akey, ghist, aclass, abox,
                                                   tscore, tclass, tbox, maxcU);
    k_sup<<<dim3(136, BB), 64, 0, stream>>>(tbox, tclass, maxcU, sup);
    k_scan<<<BB, 256, 0, stream>>>(sup, tscore, tclass, tbox, out);
}

// Round 11
// 215.780 us; speedup vs baseline: 1.0430x; 1.0430x over previous
//
#include <hip/hip_runtime.h>
#include <math.h>

typedef unsigned int u32;
typedef unsigned long long u64;

#define BB 16
#define NANCH 17064
#define NGRP 4266          // NANCH / 4
#define NTOP 1000
#define NWORD 16
#define NOUT 100
#define NBIN13 8192        // 13-bit coarse bins (fits LDS)
#define NSPLIT 17          // ceil(NANCH / 1024)

__device__ __forceinline__ u32 fmap(float v) {
    u32 u = __float_as_uint(v);
    return (u & 0x80000000u) ? ~u : (u | 0x80000000u);
}
__device__ __forceinline__ float funmap(u32 u) {
    u32 b = (u & 0x80000000u) ? (u & 0x7FFFFFFFu) : ~u;
    return __uint_as_float(b);
}

// ---------------------------------------------------------------- kernel A
// Round-5..8 proven core. NEW this round: hist zero + merge loops vectorized
// to uint4 (ds_*_b128), cutting ~17.6M scalar LDS ops kernel-wide by 4x.
__global__ void __launch_bounds__(256) k_anchor(
        const float* __restrict__ c0, const float* __restrict__ c1,
        const float* __restrict__ c2, const float* __restrict__ c3,
        const float* __restrict__ c4,
        const float* __restrict__ r0, const float* __restrict__ r1,
        const float* __restrict__ r2, const float* __restrict__ r3,
        const float* __restrict__ r4,
        u32* __restrict__ akey, int* __restrict__ aclass,
        float* __restrict__ abox, u32* __restrict__ ghist) {
    __shared__ u32 h1[NBIN13];               // 32 KB
    int tid = threadIdx.x;
    int b = blockIdx.y;
    int gt = blockIdx.x * 256 + tid;         // 4 * NGRP = 17064 used
    bool valid = gt < 4 * NGRP;

    uint4* h4 = (uint4*)h1;
    for (int i = tid; i < NBIN13 / 4; i += 256) h4[i] = make_uint4(0, 0, 0, 0);
    __syncthreads();

    if (valid) {
        int p = gt >> 2, cs = gt & 3;        // group, class-quarter
        int a = p * 4;

        const float *cp, *rp;
        int loc, wl, h, stride, half;
        if (a < 12800)      { loc = a;         wl = 7; h = 100; stride = 8;   half = 4;  cp = c0; rp = r0; }
        else if (a < 16000) { loc = a - 12800; wl = 6; h = 50;  stride = 16;  half = 8;  cp = c1; rp = r1; }
        else if (a < 16800) { loc = a - 16000; wl = 5; h = 25;  stride = 32;  half = 16; cp = c2; rp = r2; }
        else if (a < 17008) { loc = a - 16800; wl = 4; h = 13;  stride = 64;  half = 32; cp = c3; rp = r3; }
        else                { loc = a - 17008; wl = 3; h = 7;   stride = 128; half = 64; cp = c4; rp = r4; }
        int y = loc >> wl, x = loc & ((1 << wl) - 1);
        int hw = h << wl, hwq = hw >> 2;

        const float4* cb4 = (const float4*)(cp + (size_t)b * 80 * hw +
                                            (size_t)cs * 20 * hw + loc);
        // ---- issue ALL loads up front (static indices -> registers) ----
        float4 buf[20];
#pragma unroll
        for (int c = 0; c < 20; ++c) buf[c] = cb4[(size_t)c * hwq];
        const float4* rb4 = (const float4*)(rp + (size_t)b * 4 * hw + loc);
        float4 gl, gt_, gr, gb;
        if (cs == 0) {
            gl = rb4[0]; gt_ = rb4[hwq]; gr = rb4[2 * hwq]; gb = rb4[3 * hwq];
        }
        __builtin_amdgcn_sched_barrier(0);   // keep loads above the compute

        int cbase = cs * 20;
        float m0 = buf[0].x, m1 = buf[0].y, m2 = buf[0].z, m3 = buf[0].w;
        int a0 = cbase, a1 = cbase, a2 = cbase, a3 = cbase;
#pragma unroll
        for (int c = 1; c < 20; ++c) {
            float4 u = buf[c];
            int cc = cbase + c;
            if (u.x > m0) { m0 = u.x; a0 = cc; }
            if (u.y > m1) { m1 = u.y; a1 = cc; }
            if (u.z > m2) { m2 = u.z; a2 = cc; }
            if (u.w > m3) { m3 = u.w; a3 = cc; }
        }
        // stage 1: xor-1 partner; lower class-quarter wins ties
        {
            bool low = (cs & 1) == 0;
            float pm; int pa; bool tk;
            pm = __shfl_xor(m0, 1); pa = __shfl_xor(a0, 1);
            tk = low ? (m0 >= pm) : (m0 > pm); m0 = tk ? m0 : pm; a0 = tk ? a0 : pa;
            pm = __shfl_xor(m1, 1); pa = __shfl_xor(a1, 1);
            tk = low ? (m1 >= pm) : (m1 > pm); m1 = tk ? m1 : pm; a1 = tk ? a1 : pa;
            pm = __shfl_xor(m2, 1); pa = __shfl_xor(a2, 1);
            tk = low ? (m2 >= pm) : (m2 > pm); m2 = tk ? m2 : pm; a2 = tk ? a2 : pa;
            pm = __shfl_xor(m3, 1); pa = __shfl_xor(a3, 1);
            tk = low ? (m3 >= pm) : (m3 > pm); m3 = tk ? m3 : pm; a3 = tk ? a3 : pa;
        }
        // stage 2: xor-2 partner; lower half wins ties
        {
            bool low = (cs & 2) == 0;
            float pm; int pa; bool tk;
            pm = __shfl_xor(m0, 2); pa = __shfl_xor(a0, 2);
            tk = low ? (m0 >= pm) : (m0 > pm); m0 = tk ? m0 : pm; a0 = tk ? a0 : pa;
            pm = __shfl_xor(m1, 2); pa = __shfl_xor(a1, 2);
            tk = low ? (m1 >= pm) : (m1 > pm); m1 = tk ? m1 : pm; a1 = tk ? a1 : pa;
            pm = __shfl_xor(m2, 2); pa = __shfl_xor(a2, 2);
            tk = low ? (m2 >= pm) : (m2 > pm); m2 = tk ? m2 : pm; a2 = tk ? a2 : pa;
            pm = __shfl_xor(m3, 2); pa = __shfl_xor(a3, 2);
            tk = low ? (m3 >= pm) : (m3 > pm); m3 = tk ? m3 : pm; a3 = tk ? a3 : pa;
        }
        if (cs == 0) {
            int idx = b * NANCH + a;
            u32 km0 = fmap(m0), km1 = fmap(m1), km2 = fmap(m2), km3 = fmap(m3);
            *(uint4*)(akey + idx) = make_uint4(km0, km1, km2, km3);
            *(int4*)(aclass + idx) = make_int4(a0 + 1, a1 + 1, a2 + 1, a3 + 1);
            atomicAdd(&h1[km0 >> 19], 1u);
            atomicAdd(&h1[km1 >> 19], 1u);
            atomicAdd(&h1[km2 >> 19], 1u);
            atomicAdd(&h1[km3 >> 19], 1u);
            float cy = (float)(y * stride + half);
            float cx0 = (float)(x * stride + half);
            float gls[4] = {gl.x, gl.y, gl.z, gl.w};
            float gts[4] = {gt_.x, gt_.y, gt_.z, gt_.w};
            float grs[4] = {gr.x, gr.y, gr.z, gr.w};
            float gbs[4] = {gb.x, gb.y, gb.z, gb.w};
#pragma unroll
            for (int k = 0; k < 4; ++k) {
                float cx = cx0 + (float)(k * stride);
                *(float4*)(abox + (size_t)(idx + k) * 4) =
                    make_float4(cx - gls[k], cy - gts[k], cx + grs[k], cy + gbs[k]);
            }
        }
    }
    __syncthreads();
    // merge nonzero bins to global; uint4 reads (ds_read_b128, conflict-free)
    u32* gh = ghist + (size_t)b * NBIN13;
    for (int i = tid; i < NBIN13 / 4; i += 256) {
        uint4 c4v = h4[i];
        if (c4v.x | c4v.y | c4v.z | c4v.w) {
            int b4 = i * 4;
            if (c4v.x) atomicAdd(&gh[b4 + 0], c4v.x);
            if (c4v.y) atomicAdd(&gh[b4 + 1], c4v.y);
            if (c4v.z) atomicAdd(&gh[b4 + 2], c4v.z);
            if (c4v.w) atomicAdd(&gh[b4 + 3], c4v.w);
        }
    }
}

// ---------------------------------------------------------------- kernel C
// Round-8 verbatim: compaction with inline coarse threshold. 17x16 blocks
// each compute T13 from the L2-hot ghist (segment sums straight from global,
// 8-step suffix scan, 32-bin serial tail), then block-aggregated compact.
__global__ void __launch_bounds__(256) k_compact(const u32* __restrict__ akey,
                                                 const u32* __restrict__ ghist,
                                                 u32* __restrict__ ccnt,
                                                 u64* __restrict__ cand) {
    __shared__ u32 seg[256];
    __shared__ u32 binb[32];
    __shared__ int Gs;
    __shared__ u32 thrS;
    __shared__ u32 lcnt, baseoff;
    int b = blockIdx.y, s = blockIdx.x, t = threadIdx.x;
    const u32* gh = ghist + (size_t)b * NBIN13;

    // ---- inline T13: segment sums straight from global (L2-hot) ----
    u32 sum = 0;
    {
        const uint4* g4 = (const uint4*)(gh + t * 32);
#pragma unroll
        for (int j = 0; j < 8; ++j) {
            uint4 q = g4[j];
            sum += q.x + q.y + q.z + q.w;
        }
    }
    seg[t] = sum;
    if (t == 0) { Gs = 0; lcnt = 0; }
    __syncthreads();
    for (int off = 1; off < 256; off <<= 1) {        // inclusive suffix scan
        u32 v = seg[t];
        u32 add = (t + off < 256) ? seg[t + off] : 0u;
        __syncthreads();
        seg[t] = v + add;
        __syncthreads();
    }
    if (seg[t] >= NTOP) atomicMax(&Gs, t);
    __syncthreads();
    int G = Gs;
    u32 hi = (G < 255) ? seg[G + 1] : 0u;            // suffix above segment G
    if (t < 32) binb[t] = gh[G * 32 + t];
    __syncthreads();
    if (t == 0) {
        u32 acc = hi;
        int T13 = G * 32;
        for (int i = 31; i >= 0; --i) {
            acc += binb[i];
            if (acc >= NTOP) { T13 = G * 32 + i; break; }
        }
        thrS = (u32)T13;
    }
    __syncthreads();
    u32 T = thrS;                       // max bin with suffix count >= NTOP

    // ---- block-aggregated compact (round-0 proven) ----
    int base = s * 1024;
    int n = min(1024, NANCH - base);
    u32 kk[4]; u32 pos[4]; bool m[4] = {false, false, false, false};
    if (4 * t < n) {
        uint4 k4 = *(const uint4*)(akey + (size_t)b * NANCH + base + 4 * t);
        kk[0] = k4.x; kk[1] = k4.y; kk[2] = k4.z; kk[3] = k4.w;
#pragma unroll
        for (int i = 0; i < 4; ++i) {
            m[i] = (kk[i] >> 19) >= T;
            if (m[i]) pos[i] = atomicAdd(&lcnt, 1u);   // LDS atomic
        }
    }
    __syncthreads();
    if (t == 0) baseoff = atomicAdd(&ccnt[b], lcnt);   // 1 global atomic/block
    __syncthreads();
    u32 bo = baseoff;
    u64* cb = cand + (size_t)b * NANCH;
#pragma unroll
    for (int i = 0; i < 4; ++i) {
        if (m[i])
            cb[bo + pos[i]] =
                ((u64)kk[i] << 32) | (u64)(0xFFFFFFFFu - (u32)(base + 4 * t + i));
    }
}

// ---------------------------------------------------------------- kernel D
// Round-8 verbatim: exact rank among candidates; 8-way-unrolled LDS scan;
// 14x16 blocks (3584 threads/batch >= typical C ~3400 at coarse threshold).
__global__ void __launch_bounds__(256) k_rank(
        const u64* __restrict__ cand, const u32* __restrict__ ccnt,
        const int* __restrict__ aclass, const float* __restrict__ abox,
        float* __restrict__ tscore, int* __restrict__ tclass,
        float* __restrict__ tbox, u32* __restrict__ maxcU) {
    __shared__ u64 tile[2048];          // 16 KB
    int b = blockIdx.y, tid = threadIdx.x;
    int C = (int)ccnt[b];
    const u64* ck = cand + (size_t)b * NANCH;
    for (int base = blockIdx.x * 256; base < C; base += gridDim.x * 256) {
        int i = base + tid;
        bool have = i < C;
        u64 my = have ? ck[i] : 0ull;
        int rank = 0;
        for (int t0 = 0; t0 < C; t0 += 2048) {
            int nt = min(2048, C - t0);
            __syncthreads();
            for (int j = tid; j < nt; j += 256) tile[j] = ck[t0 + j];
            __syncthreads();
            int q0 = 0, q1 = 0, q2 = 0, q3 = 0, q4 = 0, q5 = 0, q6 = 0, q7 = 0;
            int j = 0;
            for (; j + 8 <= nt; j += 8) {
                u64 v0 = tile[j + 0], v1 = tile[j + 1];
                u64 v2 = tile[j + 2], v3 = tile[j + 3];
                u64 v4 = tile[j + 4], v5 = tile[j + 5];
                u64 v6 = tile[j + 6], v7 = tile[j + 7];
                q0 += v0 > my; q1 += v1 > my; q2 += v2 > my; q3 += v3 > my;
                q4 += v4 > my; q5 += v5 > my; q6 += v6 > my; q7 += v7 > my;
            }
            for (; j < nt; ++j) q0 += tile[j] > my;
            rank += ((q0 + q1) + (q2 + q3)) + ((q4 + q5) + (q6 + q7));
        }
        u32 mymax = 0;  // identity under monotone map
        if (have && rank < NTOP) {
            u32 a = 0xFFFFFFFFu - (u32)(my & 0xFFFFFFFFull);
            int src = b * NANCH + (int)a;
            int dst = b * NTOP + rank;
            float logit = funmap((u32)(my >> 32));
            float sc = 1.0f / (1.0f + expf(-logit));
            float b0 = abox[src * 4 + 0], b1 = abox[src * 4 + 1];
            float b2 = abox[src * 4 + 2], b3 = abox[src * 4 + 3];
            tscore[dst] = sc;
            tclass[dst] = aclass[src];
            tbox[dst * 4 + 0] = b0;
            tbox[dst * 4 + 1] = b1;
            tbox[dst * 4 + 2] = b2;
            tbox[dst * 4 + 3] = b3;
            if (sc >= 0.05f)
                mymax = fmap(fmaxf(fmaxf(b0, b1), fmaxf(b2, b3)));
        }
        for (int off = 32; off > 0; off >>= 1) {
            u32 o = (u32)__shfl_down((int)mymax, off);
            mymax = mymax > o ? mymax : o;
        }
        if ((tid & 63) == 0) atomicMax(&maxcU[b], mymax);
    }
}

// ---------------------------------------------------------------- kernel F
// upper-triangle tiles only (136 of 256). Divide-free DIoU test:
// diou > 0.6  <=>  inter*odg - idg*U > 0.6*U*odg   (U>0, odg>0)  [proven r2]
__global__ void k_sup(const float* __restrict__ tbox, const int* __restrict__ tclass,
                      const u32* __restrict__ maxcU, u64* __restrict__ sup) {
    int u = blockIdx.x, b = blockIdx.y;
    int ti = 0, rem = u;
    while (rem >= NWORD - ti) { rem -= NWORD - ti; ++ti; }
    int tj = ti + rem;
    int t = threadIdx.x;
    __shared__ double jx1[64], jy1[64], jx2[64], jy2[64], jcx[64], jcy[64], jar[64];
    double mc1 = (double)funmap(maxcU[b]) + 1.0;
    int j = tj * 64 + t;
    if (j < NTOP) {
        const float* bx = tbox + (size_t)(b * NTOP + j) * 4;
        double o = (double)tclass[b * NTOP + j] * mc1;
        double x1 = (double)bx[0] + o, y1 = (double)bx[1] + o;
        double x2 = (double)bx[2] + o, y2 = (double)bx[3] + o;
        jx1[t] = x1; jy1[t] = y1; jx2[t] = x2; jy2[t] = y2;
        jcx[t] = (x1 + x2) * 0.5; jcy[t] = (y1 + y2) * 0.5;
        jar[t] = (x2 - x1 + 1.0) * (y2 - y1 + 1.0);
    }
    __syncthreads();
    int i = ti * 64 + t;
    if (i >= NTOP) return;
    const float* bx = tbox + (size_t)(b * NTOP + i) * 4;
    double o = (double)tclass[b * NTOP + i] * mc1;
    double ix1 = (double)bx[0] + o, iy1 = (double)bx[1] + o;
    double ix2 = (double)bx[2] + o, iy2 = (double)bx[3] + o;
    double icx = (ix1 + ix2) * 0.5, icy = (iy1 + iy2) * 0.5;
    double iar = (ix2 - ix1 + 1.0) * (iy2 - iy1 + 1.0);
    u64 bits = 0;
    int jbase = tj * 64;
    for (int jj = 0; jj < 64; ++jj) {
        int jg = jbase + jj;
        if (jg >= NTOP) break;
        if (jg <= i) continue;
        double xm = fmax(ix1, jx1[jj]), ym = fmax(iy1, jy1[jj]);
        double xM = fmin(ix2, jx2[jj]), yM = fmin(iy2, jy2[jj]);
        double inter = fmax(xM - xm, 0.0) * fmax(yM - ym, 0.0);
        double U = iar + jar[jj] - inter;
        double dx = icx - jcx[jj], dy = icy - jcy[jj];
        double idg = dx * dx + dy * dy;
        double ox = fmax(ix2, jx2[jj]) - fmin(ix1, jx1[jj]);
        double oy = fmax(iy2, jy2[jj]) - fmin(iy1, jy1[jj]);
        double odg = fmax(ox * ox + oy * oy, 1e-12);
        if (inter * odg - idg * U > 0.6 * (U * odg)) bits |= (1ull << jj);
    }
    sup[(size_t)(b * NTOP + i) * NWORD + tj] = bits;
}

// ---------------------------------------------------------------- kernel G
// Wave-synchronous greedy scan; 256 threads — waves 1-3 double-buffer
// prefetch tile t+1 while wave 0 scans tile t. [round-5 proven]
__global__ void __launch_bounds__(256) k_scan(
        const u64* __restrict__ sup, const float* __restrict__ tscore,
        const int* __restrict__ tclass, const float* __restrict__ tbox,
        float* __restrict__ out) {
    int b = blockIdx.x, tid = threadIdx.x;
    int lane = tid & 63;
    __shared__ u64 tl[2][64 * 17];           // double-buffered padded tiles
    __shared__ float sc_s[1024];
    __shared__ int kept_lds[NOUT];
    __shared__ int kept_sh;
    const u64* supb = sup + (size_t)b * NTOP * NWORD;
    for (int i = tid; i < 1024; i += 256)
        sc_s[i] = (i < NTOP) ? tscore[b * NTOP + i] : -1.0f;
    if (tid == 0) kept_sh = 0;
    // prologue: all threads load tile 0
    for (int q = 0; q < 4; ++q) {
        int e = q * 256 + tid;
        int rr = e >> 4, w = e & 15;
        tl[0][rr * 17 + w] = (rr < NTOP) ? supb[(size_t)rr * 16 + w] : 0ull;
    }
    __syncthreads();
    u64 remw = 0;                            // wave0: lane w<16 = removed word w
    int kept = 0;
    for (int t = 0; t < NWORD; ++t) {
        int cur = t & 1;
        if (tid >= 64) {                     // waves 1-3: prefetch tile t+1
            if (t + 1 < NWORD) {
                int r1 = (t + 1) * 64;
                for (int e = tid - 64; e < 1024; e += 192) {
                    int rr = r1 + (e >> 4), w = e & 15;
                    tl[cur ^ 1][(e >> 4) * 17 + w] =
                        (rr < NTOP) ? supb[(size_t)rr * 16 + w] : 0ull;
                }
            }
        } else {                             // wave 0: greedy scan of tile t
            int r0 = t * 64;
            int r = r0 + lane;               // r <= 1023, sc_s padded
            float s = sc_s[r];
            u64 vmask = __ballot(s >= 0.05f);
            u64 M = tl[cur][lane * 17 + t];
            u64 rem_t = __shfl(remw, t);
            u64 cnd = vmask & ~rem_t;
            u64 keepmask = 0;
            while (cnd) {
                int k = __ffsll(cnd) - 1;
                keepmask |= 1ull << k;
                if (lane == 0) kept_lds[kept] = r0 + k;
                ++kept;
                if (kept >= NOUT) break;
                u64 Mk = __shfl(M, k);
                cnd &= ~(Mk | (1ull << k));
            }
            if (lane < NWORD) {
                u64 km = keepmask;
                while (km) {
                    int k = __ffsll(km) - 1;
                    km &= km - 1;
                    remw |= tl[cur][k * 17 + lane];
                }
            }
            if (lane == 0) kept_sh = kept;
        }
        __syncthreads();
        if (kept_sh >= NOUT) break;          // block-uniform
    }
    float* os = out + b * NOUT;
    float* oc = out + BB * NOUT + b * NOUT;
    float* ob = out + 2 * BB * NOUT + (size_t)b * NOUT * 4;
    for (int i = tid; i < NOUT; i += 256) { os[i] = -2.0f; oc[i] = -2.0f; }
    for (int i = tid; i < NOUT * 4; i += 256) ob[i] = -2.0f;
    __syncthreads();
    int ncopy = kept_sh < NOUT ? kept_sh : NOUT;
    for (int r = tid; r < ncopy; r += 256) {
        int i = kept_lds[r];
        os[r] = tscore[b * NTOP + i];
        oc[r] = (float)tclass[b * NTOP + i];
        ob[r * 4 + 0] = tbox[(size_t)(b * NTOP + i) * 4 + 0];
        ob[r * 4 + 1] = tbox[(size_t)(b * NTOP + i) * 4 + 1];
        ob[r * 4 + 2] = tbox[(size_t)(b * NTOP + i) * 4 + 2];
        ob[r * 4 + 3] = tbox[(size_t)(b * NTOP + i) * 4 + 3];
    }
}

// ---------------------------------------------------------------- launch
extern "C" void kernel_launch(void* const* d_in, const int* in_sizes, int n_in,
                              void* d_out, int out_size, void* d_ws, size_t ws_size,
                              hipStream_t stream) {
    (void)in_sizes; (void)n_in; (void)out_size; (void)ws_size;
    const float* cls[5];
    const float* reg[5];
    for (int i = 0; i < 5; ++i) {
        cls[i] = (const float*)d_in[2 * i];
        reg[i] = (const float*)d_in[2 * i + 1];
    }
    float* out = (float*)d_out;

    char* ws = (char*)d_ws;
    // ---- zero-init region (single memset): ghist + ccnt + maxcU ----
    u32* ghist = (u32*)ws;           ws += (size_t)BB * NBIN13 * sizeof(u32); // 512 KB
    u32* ccnt = (u32*)ws;            ws += 64;
    u32* maxcU = (u32*)ws;           ws += 64;
    size_t zbytes = (size_t)BB * NBIN13 * sizeof(u32) + 128;
    // ---- rest (written before read) ----
    u64* cand = (u64*)ws;            ws += (size_t)BB * NANCH * sizeof(u64);
    u64* sup = (u64*)ws;             ws += (size_t)BB * NTOP * NWORD * sizeof(u64);
    u32* akey = (u32*)ws;            ws += (size_t)BB * NANCH * sizeof(u32);
    int* aclass = (int*)ws;          ws += (size_t)BB * NANCH * sizeof(int);
    float* abox = (float*)ws;        ws += (size_t)BB * NANCH * 4 * sizeof(float);
    float* tscore = (float*)ws;      ws += (size_t)BB * NTOP * sizeof(float);
    int* tclass = (int*)ws;          ws += (size_t)BB * NTOP * sizeof(int);
    float* tbox = (float*)ws;        ws += (size_t)BB * NTOP * 4 * sizeof(float);

    hipMemsetAsync(ghist, 0, zbytes, stream);

    k_anchor<<<dim3((4 * NGRP + 255) / 256, BB), 256, 0, stream>>>(
        cls[0], cls[1], cls[2], cls[3], cls[4],
        reg[0], reg[1], reg[2], reg[3], reg[4],
        akey, aclass, abox, ghist);
    k_compact<<<dim3(NSPLIT, BB), 256, 0, stream>>>(akey, ghist, ccnt, cand);
    k_rank<<<dim3(14, BB), 256, 0, stream>>>(cand, ccnt, aclass, abox,
                                             tscore, tclass, tbox, maxcU);
    k_sup<<<dim3(136, BB), 64, 0, stream>>>(tbox, tclass, maxcU, sup);
    k_scan<<<BB, 256, 0, stream>>>(sup, tscore, tclass, tbox, out);
}